// Round 4
// baseline (167.290 us; speedup 1.0000x reference)
//
#include <hip/hip_runtime.h>

#define NCLS 91
#define NP (NCLS * NCLS)      // 8281 pair bins
#define NHIST (3 * NCLS)      // ws: cnt_in[0..90] | cnt_tg[91..181] | inter[182..272]
#define NBLK 1024
#define BS 512

__device__ __forceinline__ void proc4(unsigned int* __restrict__ ph, float4 f, int4 t) {
    int a0 = (int)f.x, a1 = (int)f.y, a2 = (int)f.z, a3 = (int)f.w;
    atomicAdd(&ph[a0 * NCLS + t.x], 1u);
    atomicAdd(&ph[a1 * NCLS + t.y], 1u);
    atomicAdd(&ph[a2 * NCLS + t.z], 1u);
    atomicAdd(&ph[a3 * NCLS + t.w], 1u);
}

__global__ __launch_bounds__(BS, 8) void miou_hist(const float* __restrict__ inp,
                                                   const int* __restrict__ tgt,
                                                   unsigned int* __restrict__ ws,
                                                   int n4) {
    __shared__ unsigned int ph[NP];   // 33,124 B -> 4 blocks/CU, 100% occupancy
    for (int i = threadIdx.x; i < NP; i += BS) ph[i] = 0u;
    __syncthreads();

    int tid = blockIdx.x * BS + threadIdx.x;
    int stride = gridDim.x * BS;
    const float4* in4 = (const float4*)inp;
    const int4* tg4 = (const int4*)tgt;

    int i = tid;
    for (; i + stride < n4; i += 2 * stride) {
        float4 f0 = in4[i];
        int4 t0 = tg4[i];
        float4 f1 = in4[i + stride];
        int4 t1 = tg4[i + stride];
        proc4(ph, f0, t0);
        proc4(ph, f1, t1);
    }
    if (i < n4) proc4(ph, in4[i], tg4[i]);
    __syncthreads();

    // Fold: rows -> cnt_in (wave 0-1), cols -> cnt_tg (wave 2-3), diag -> inter (wave 4).
    int t = threadIdx.x;
    if (t < NCLS) {
        unsigned int s = 0;
        const unsigned int* p = ph + t * NCLS;
        for (int k = 0; k < NCLS; ++k) s += p[k];
        if (s) atomicAdd(&ws[t], s);
    } else if (t >= 128 && t < 128 + NCLS) {
        int c = t - 128;
        unsigned int s = 0;
        for (int a = 0; a < NCLS; ++a) s += ph[a * NCLS + c];
        if (s) atomicAdd(&ws[NCLS + c], s);
    } else if (t >= 256 && t < 256 + NCLS) {
        int d = t - 256;
        unsigned int v = ph[d * (NCLS + 1)];
        if (v) atomicAdd(&ws[2 * NCLS + d], v);
    }
}

__global__ void miou_finalize(const unsigned int* __restrict__ ws,
                              const int* __restrict__ smooth_p,
                              float* __restrict__ out) {
    int lane = threadIdx.x;  // 64 threads
    float s = (float)(*smooth_p);
    float acc = 0.f;
    for (int c = 1 + lane; c < NCLS; c += 64) {
        float ci = (float)ws[c];
        float ct = (float)ws[NCLS + c];
        float it = (float)ws[2 * NCLS + c];
        float un = ci + ct - it;
        acc += (it + s) / (un + s);
    }
    #pragma unroll
    for (int off = 32; off; off >>= 1) acc += __shfl_down(acc, off);
    if (lane == 0) out[0] = acc / (float)(NCLS - 1);
}

extern "C" void kernel_launch(void* const* d_in, const int* in_sizes, int n_in,
                              void* d_out, int out_size, void* d_ws, size_t ws_size,
                              hipStream_t stream) {
    const float* inp = (const float*)d_in[0];
    const int* tgt = (const int*)d_in[1];
    const int* smooth_p = (const int*)d_in[2];
    float* out = (float*)d_out;
    unsigned int* ws = (unsigned int*)d_ws;

    int n = in_sizes[0];      // 64*512*512 = 16,777,216 (divisible by 4)
    int n4 = n >> 2;

    hipMemsetAsync(ws, 0, NHIST * sizeof(unsigned int), stream);
    miou_hist<<<NBLK, BS, 0, stream>>>(inp, tgt, ws, n4);
    miou_finalize<<<1, 64, 0, stream>>>(ws, smooth_p, out);
}

// Round 5
// 160.274 us; speedup vs baseline: 1.0438x; 1.0438x over previous
//
#include <hip/hip_runtime.h>

#define NCLS 91
#define NP (NCLS * NCLS)          // 8281 pair bins
#define NPPAD 8320                // padded to multiple of 4 words for uint4 zeroing
#define NHIST (3 * NCLS)          // ws: cnt_in | cnt_tg | inter
#define NBLK 1024
#define BS 256

__device__ __forceinline__ void proc4(unsigned int* __restrict__ ph, float4 f, int4 t) {
    int a0 = (int)f.x, a1 = (int)f.y, a2 = (int)f.z, a3 = (int)f.w;
    atomicAdd(&ph[a0 * NCLS + t.x], 1u);
    atomicAdd(&ph[a1 * NCLS + t.y], 1u);
    atomicAdd(&ph[a2 * NCLS + t.z], 1u);
    atomicAdd(&ph[a3 * NCLS + t.w], 1u);
}

__global__ __launch_bounds__(BS, 4) void miou_hist(const float* __restrict__ inp,
                                                   const int* __restrict__ tgt,
                                                   unsigned int* __restrict__ ws,
                                                   int n4) {
    __shared__ unsigned int ph[NPPAD];
    uint4* z = (uint4*)ph;
    #pragma unroll 2
    for (int i = threadIdx.x; i < NPPAD / 4; i += BS) z[i] = make_uint4(0u, 0u, 0u, 0u);
    __syncthreads();

    const float4* in4 = (const float4*)inp;
    const int4* tg4 = (const int4*)tgt;
    const int i0 = blockIdx.x * BS + threadIdx.x;
    const int stride = NBLK * BS;

    float4 fa0, fa1, fa2, fa3, fb0, fb1, fb2, fb3;
    int4 ta0, ta1, ta2, ta3, tb0, tb1, tb2, tb3;

#define LOADC(B, C)                                                         \
    do {                                                                    \
        int _b = i0 + (C) * 4 * stride;                                     \
        f##B##0 = in4[_b];              t##B##0 = tg4[_b];                  \
        f##B##1 = in4[_b + stride];     t##B##1 = tg4[_b + stride];         \
        f##B##2 = in4[_b + 2 * stride]; t##B##2 = tg4[_b + 2 * stride];     \
        f##B##3 = in4[_b + 3 * stride]; t##B##3 = tg4[_b + 3 * stride];     \
        __builtin_amdgcn_sched_group_barrier(0x20, 8, 0); /* pin 8 VMEM_READ */ \
    } while (0)

#define PROC(B)                                                             \
    do {                                                                    \
        proc4(ph, f##B##0, t##B##0);                                        \
        proc4(ph, f##B##1, t##B##1);                                        \
        proc4(ph, f##B##2, t##B##2);                                        \
        proc4(ph, f##B##3, t##B##3);                                        \
    } while (0)

    int i = i0;
    if (i0 + 15 * stride < n4) {
        // Software pipeline: chunks 0..3, two register banks, loads issued
        // two chunks ahead of their atomics (16 dwordx4 in flight).
        LOADC(a, 0);
        LOADC(b, 1);
        PROC(a);
        LOADC(a, 2);
        PROC(b);
        LOADC(b, 3);
        PROC(a);
        PROC(b);
        i = i0 + 16 * stride;
    }
    for (; i < n4; i += stride) proc4(ph, in4[i], tg4[i]);   // generic tail (empty here)
#undef LOADC
#undef PROC

    __syncthreads();

    // Fold. Waves 0-1: row sums (cnt_in) + diagonal (inter). Waves 2-3: col sums (cnt_tg).
    int t = threadIdx.x;
    if (t < NCLS) {
        const unsigned int* p = ph + t * NCLS;
        unsigned int s0 = 0, s1 = 0, s2 = 0, s3 = 0;
        int k = 0;
        for (; k + 3 < NCLS; k += 4) { s0 += p[k]; s1 += p[k+1]; s2 += p[k+2]; s3 += p[k+3]; }
        for (; k < NCLS; ++k) s0 += p[k];
        unsigned int s = s0 + s1 + s2 + s3;
        if (s) atomicAdd(&ws[t], s);
        unsigned int d = p[t];
        if (d) atomicAdd(&ws[2 * NCLS + t], d);
    } else if (t >= 128 && t < 128 + NCLS) {
        int c = t - 128;
        unsigned int s0 = 0, s1 = 0, s2 = 0, s3 = 0;
        int a = 0;
        for (; a + 3 < NCLS; a += 4) {
            s0 += ph[a * NCLS + c];
            s1 += ph[(a + 1) * NCLS + c];
            s2 += ph[(a + 2) * NCLS + c];
            s3 += ph[(a + 3) * NCLS + c];
        }
        for (; a < NCLS; ++a) s0 += ph[a * NCLS + c];
        unsigned int s = s0 + s1 + s2 + s3;
        if (s) atomicAdd(&ws[NCLS + c], s);
    }
}

__global__ void miou_finalize(const unsigned int* __restrict__ ws,
                              const int* __restrict__ smooth_p,
                              float* __restrict__ out) {
    int lane = threadIdx.x;  // 64 threads
    float s = (float)(*smooth_p);
    float acc = 0.f;
    for (int c = 1 + lane; c < NCLS; c += 64) {
        float ci = (float)ws[c];
        float ct = (float)ws[NCLS + c];
        float it = (float)ws[2 * NCLS + c];
        float un = ci + ct - it;
        acc += (it + s) / (un + s);
    }
    #pragma unroll
    for (int off = 32; off; off >>= 1) acc += __shfl_down(acc, off);
    if (lane == 0) out[0] = acc / (float)(NCLS - 1);
}

extern "C" void kernel_launch(void* const* d_in, const int* in_sizes, int n_in,
                              void* d_out, int out_size, void* d_ws, size_t ws_size,
                              hipStream_t stream) {
    const float* inp = (const float*)d_in[0];
    const int* tgt = (const int*)d_in[1];
    const int* smooth_p = (const int*)d_in[2];
    float* out = (float*)d_out;
    unsigned int* ws = (unsigned int*)d_ws;

    int n = in_sizes[0];      // 64*512*512 = 16,777,216
    int n4 = n >> 2;

    hipMemsetAsync(ws, 0, NHIST * sizeof(unsigned int), stream);
    miou_hist<<<NBLK, BS, 0, stream>>>(inp, tgt, ws, n4);
    miou_finalize<<<1, 64, 0, stream>>>(ws, smooth_p, out);
}